// Round 7
// baseline (269.156 us; speedup 1.0000x reference)
//
#include <hip/hip_runtime.h>

// LSTM fused kernel for MI355X (gfx950) — round 7.
// B=4096, S=256, H=64, input dim 4 (from Linear(1->4)+tanh).
// grid=256 blocks, 512 threads (8 waves = 2/SIMD), TB=16 rows/block split as
// TWO independent 8-row half-LSTMs (waves 0-3 / 4-7) so co-resident waves
// overlap MFMA and transcendental phases (R6 showed ~490 cyc/step stall @ 1 wave/SIMD).
// Packed-A MFMA: A rows 0-7 = h_hi, rows 8-15 = h_lo -> each MFMA vs W_hi/W_lo
// yields hi+lo partial rows simultaneously; shfl_xor(32) both redistributes ew
// cells AND performs the hi+lo row reduction. 20 MFMA/wave/step, full 4-term
// split product (fp32-exact h @ W_hh).

typedef __attribute__((ext_vector_type(8))) __bf16 bf16x8;
typedef __attribute__((ext_vector_type(4))) float f32x4;
typedef __attribute__((ext_vector_type(2))) float f32x2;

#define S_LEN 256
#define TB 16
#define CHUNK 64
#define LOG2E 1.4426950408889634f

#if defined(__has_builtin) && __has_builtin(__builtin_amdgcn_exp2f)
#define EXP2F(x) __builtin_amdgcn_exp2f(x)
#else
#define EXP2F(x) exp2f(x)
#endif
#if defined(__has_builtin) && __has_builtin(__builtin_amdgcn_rcpf)
#define RCPF(x) __builtin_amdgcn_rcpf(x)
#else
#define RCPF(x) (1.0f / (x))
#endif

__device__ __forceinline__ float fast_tanh(float x) {
    float e = EXP2F(2.0f * LOG2E * x);
    return 1.0f - 2.0f * RCPF(e + 1.0f);
}

#define MFMA16(A, B, C) __builtin_amdgcn_mfma_f32_16x16x32_bf16((A), (B), (C), 0, 0, 0)

// One LSTM step for this thread's half. RB/WB: hbuf ping-pong. TLOC = t & 63.
#define STEP(RB, WB, TLOC) do {                                                  \
    bf16x8 ap0 = *(const bf16x8*)&hbuf[hv][RB][ahl][0][kg][arow][0];             \
    bf16x8 ap1 = *(const bf16x8*)&hbuf[hv][RB][ahl][1][kg][arow][0];             \
    bf16x8 fa  = *(const bf16x8*)&fcfrag[TLOC][farow][0];                        \
    if (col >= 8) fa = zero8;   /* A rows 8-15 of gx must stay 0 */              \
    f32x4 acc[4];                                                                \
    _Pragma("unroll")                                                            \
    for (int n = 0; n < 4; ++n) {                                                \
        f32x4 a = MFMA16(fa,  whx[n],      biasq[n]);  /* gx + bias (rows<8) */  \
        a       = MFMA16(ap0, whh_h[n][0], a);   /* hi&lo rows vs W_hi ks0 */    \
        a       = MFMA16(ap1, whh_h[n][1], a);   /* ks1 */                       \
        a       = MFMA16(ap0, whh_l[n][0], a);   /* hi&lo rows vs W_lo ks0 */    \
        a       = MFMA16(ap1, whh_l[n][1], a);   /* ks1 */                       \
        acc[n] = a;                                                              \
    }                                                                            \
    /* D rows r (hi part) + r+8 (lo part) summed via the xor-32 exchange; */     \
    /* kg0->rows{0,1}, kg2->{2,3}, kg1->{4,5}, kg3->{6,7}, 2 cells/lane  */      \
    float gate[4][2];                                                            \
    _Pragma("unroll")                                                            \
    for (int n = 0; n < 4; ++n) {                                                \
        float own0 = upper ? acc[n][2] : acc[n][0];                              \
        float own1 = upper ? acc[n][3] : acc[n][1];                              \
        float snd0 = upper ? acc[n][0] : acc[n][2];                              \
        float snd1 = upper ? acc[n][1] : acc[n][3];                              \
        gate[n][0] = own0 + __shfl_xor(snd0, 32);                                \
        gate[n][1] = own1 + __shfl_xor(snd1, 32);                                \
    }                                                                            \
    _Pragma("unroll")                                                            \
    for (int r = 0; r < 2; ++r) {                                                \
        /* preacts pre-scaled by LOG2E (2*LOG2E for g-gate) */                   \
        float ei = EXP2F(-gate[0][r]); float iv = RCPF(1.0f + ei);               \
        float ef = EXP2F(-gate[1][r]); float fv = RCPF(1.0f + ef);               \
        float eg = EXP2F( gate[2][r]); float gv = 1.0f - 2.0f * RCPF(1.0f + eg); \
        float eo = EXP2F(-gate[3][r]); float ov = RCPF(1.0f + eo);               \
        float cv = fv * cst[r] + iv * gv; cst[r] = cv;                           \
        float ec = EXP2F((2.0f * LOG2E) * cv);                                   \
        float th = 1.0f - 2.0f * RCPF(1.0f + ec);                                \
        float hvv = ov * th; hlast[r] = hvv;                                     \
        __bf16 hh = (__bf16)hvv; __bf16 hl = (__bf16)(hvv - (float)hh);          \
        hbuf[hv][WB][0][uks][ukg][row_base + r][up] = hh;                        \
        hbuf[hv][WB][1][uks][ukg][row_base + r][up] = hl;                        \
    }                                                                            \
    __syncthreads();                                                             \
} while (0)

__global__ __launch_bounds__(512, 1)
void lstm_fused(const float* __restrict__ x,
                const float* __restrict__ W1, const float* __restrict__ b1,
                const float* __restrict__ W_ih, const float* __restrict__ W_hh,
                const float* __restrict__ b_ih, const float* __restrict__ b_hh,
                const float* __restrict__ W2, const float* __restrict__ b2,
                float* __restrict__ out)
{
    // fc1 A-fragments: [t][global row 0..15][ f_hi(4) | f_lo(4) ]   (16 KB)
    __shared__ __bf16 fcfrag[CHUNK][TB][8];
    // h per half, ping-pong, hi/lo planes, k-grouped:
    // [half][buf][hl][ks][kg][row 0..7][j]   (8 KB total)
    __shared__ __bf16 hbuf[2][2][2][2][4][8][8];
    // final h for output projection: [unit][global row]   (4 KB)
    __shared__ float hfin[64][TB];

    const int tid  = threadIdx.x;
    const int lane = tid & 63;
    const int wv8  = tid >> 6;      // wave 0..7
    const int hv   = wv8 >> 2;      // half 0/1 (rows 0-7 / 8-15)
    const int wl   = wv8 & 3;       // wave within half
    const int col  = lane & 15;     // A-row / D-col
    const int kg   = lane >> 4;     // k-group 0..3
    const int b0   = blockIdx.x * TB;

    const int  ahl   = col >> 3;          // packed-A plane (0=hi rows, 1=lo rows)
    const int  arow  = col & 7;
    const int  farow = 8 * hv + (col & 7);
    const bool upper = (kg >= 2);
    const int  row_base = (kg & 1) * 4 + (kg >> 1) * 2;   // kg0->0,kg1->4,kg2->2,kg3->6
    const int  u   = 16 * wl + col;       // this lane's h-unit
    const int  uks = u >> 5, ukg = (u >> 3) & 3, up = u & 7;

    bf16x8 zero8;
    #pragma unroll
    for (int j = 0; j < 8; ++j) zero8[j] = (__bf16)0.0f;

    // ---- weights (LOG2E-pre-scaled), resident in VGPRs ----
    bf16x8 whh_h[4][2], whh_l[4][2];  // W_hh hi/lo per gate-tile/kstep
    bf16x8 whx[4];                    // gx B-frag: kg0=[Whi|Whi], kg1=[Wlo|Wlo], else 0
    f32x4  biasq[4];                  // scaled bias splat; ZERO on kg>=2 (rows 8-15)

    #pragma unroll
    for (int n = 0; n < 4; ++n) {
        const int g = 16 * (wl + 4 * n) + col;          // n: 0=i,1=f,2=g,3=o
        const float sc = (n == 2) ? (2.0f * LOG2E) : LOG2E;
        #pragma unroll
        for (int ks = 0; ks < 2; ++ks) {
            const float* wp = &W_hh[g * 64 + ks * 32 + kg * 8];
            #pragma unroll
            for (int j = 0; j < 8; ++j) {
                float wf  = sc * wp[j];
                __bf16 hi = (__bf16)wf;
                whh_h[n][ks][j] = hi;
                whh_l[n][ks][j] = (__bf16)(wf - (float)hi);
            }
        }
        whx[n] = zero8;
        if (kg < 2) {
            #pragma unroll
            for (int j = 0; j < 4; ++j) {
                float wf  = sc * W_ih[g * 4 + j];
                __bf16 hi = (__bf16)wf;
                __bf16 v  = (kg == 0) ? hi : (__bf16)(wf - (float)hi);
                whx[n][j] = v; whx[n][j + 4] = v;
            }
        }
        const float bs = (kg < 2) ? sc * (b_ih[g] + b_hh[g]) : 0.0f;
        biasq[n][0] = bs; biasq[n][1] = bs; biasq[n][2] = bs; biasq[n][3] = bs;
    }

    // zero ALL of hbuf (8 KB = 512 f32x4): h0 = 0 for both halves/buffers
    {
        f32x4 zv = {0.f, 0.f, 0.f, 0.f};
        ((f32x4*)&hbuf[0][0][0][0][0][0][0])[tid] = zv;
    }

    float w1r[4], b1r[4];
    #pragma unroll
    for (int j = 0; j < 4; ++j) { w1r[j] = W1[j]; b1r[j] = b1[j]; }

    f32x2 cst = {0.f, 0.f};
    float hlast[2];

    for (int t = 0; t < S_LEN; t += 2) {
        if ((t & (CHUNK - 1)) == 0) {
            __syncthreads();   // prior chunk's fcfrag reads done (covers init at t=0)
            const int rr = tid & 15;
            const int tq = tid >> 4;         // 0..31, 2 steps each
            f32x2 xv = *(const f32x2*)&x[(b0 + rr) * S_LEN + t + tq * 2];
            #pragma unroll
            for (int tl = 0; tl < 2; ++tl) {
                bf16x8 v;
                #pragma unroll
                for (int j = 0; j < 4; ++j) {
                    float fc  = fast_tanh(xv[tl] * w1r[j] + b1r[j]);
                    __bf16 hi = (__bf16)fc;
                    v[j]     = hi;
                    v[j + 4] = (__bf16)(fc - (float)hi);
                }
                *(bf16x8*)&fcfrag[tq * 2 + tl][rr][0] = v;
            }
            __syncthreads();
        }
        STEP(0, 1, (t & (CHUNK - 1)));
        STEP(1, 0, ((t + 1) & (CHUNK - 1)));
    }

    // epilogue: out[b] = h_last . W2 + b2
    hfin[u][8 * hv + row_base + 0] = hlast[0];
    hfin[u][8 * hv + row_base + 1] = hlast[1];
    __syncthreads();
    if (tid < TB) {
        float s = b2[0];
        #pragma unroll
        for (int uu = 0; uu < 64; ++uu) s += hfin[uu][tid] * W2[uu];
        out[b0 + tid] = s;
    }
}

extern "C" void kernel_launch(void* const* d_in, const int* in_sizes, int n_in,
                              void* d_out, int out_size, void* d_ws, size_t ws_size,
                              hipStream_t stream) {
    (void)in_sizes; (void)n_in; (void)d_ws; (void)ws_size; (void)out_size;
    const float* x    = (const float*)d_in[0];
    const float* W1   = (const float*)d_in[1];
    const float* b1   = (const float*)d_in[2];
    const float* W_ih = (const float*)d_in[3];
    const float* W_hh = (const float*)d_in[4];
    const float* b_ih = (const float*)d_in[5];
    const float* b_hh = (const float*)d_in[6];
    const float* W2   = (const float*)d_in[7];
    const float* b2   = (const float*)d_in[8];
    float* out = (float*)d_out;
    lstm_fused<<<4096 / TB, 512, 0, stream>>>(x, W1, b1, W_ih, W_hh, b_ih, b_hh, W2, b2, out);
}

// Round 8
// 245.860 us; speedup vs baseline: 1.0948x; 1.0948x over previous
//
#include <hip/hip_runtime.h>

// LSTM fused kernel for MI355X (gfx950) — round 8.
// B=4096, S=256, H=64, input dim 4 (from Linear(1->4)+tanh).
// grid=512, TB=8 rows/block, 256 threads (4 waves), 2 INDEPENDENT blocks/CU
// (separate barriers -> real phase overlap; R7's co-barriered halves failed).
// Interleaved packed-A: A-row 2r = h_hi[r], 2r+1 = h_lo[r] -> preact row r =
// acc[2j]+acc[2j+1] (LANE-LOCAL pair sum, no shuffles), exact 4-term
// (h_hi+h_lo)@(W_hi+W_lo). 20 MFMA/wave-step.
// Fused-rcp cell: 7 transcendentals/cell (was 10) via common denominators,
// args clamped +-30 so nothing overflows.

typedef __attribute__((ext_vector_type(8))) __bf16 bf16x8;
typedef __attribute__((ext_vector_type(4))) float f32x4;
typedef __attribute__((ext_vector_type(2))) float f32x2;

#define S_LEN 256
#define TB 8
#define CHUNK 64
#define LOG2E 1.4426950408889634f
#define TWO_LOG2E 2.8853900817779268f

#if defined(__has_builtin) && __has_builtin(__builtin_amdgcn_exp2f)
#define EXP2F(x) __builtin_amdgcn_exp2f(x)
#else
#define EXP2F(x) exp2f(x)
#endif
#if defined(__has_builtin) && __has_builtin(__builtin_amdgcn_rcpf)
#define RCPF(x) __builtin_amdgcn_rcpf(x)
#else
#define RCPF(x) (1.0f / (x))
#endif

__device__ __forceinline__ float clamp30(float x) {
    return fminf(fmaxf(x, -30.0f), 30.0f);   // v_med3_f32
}
__device__ __forceinline__ float fast_tanh(float x) {
    float e = EXP2F(TWO_LOG2E * x);
    return 1.0f - 2.0f * RCPF(e + 1.0f);
}

#define MFMA16(A, B, C) __builtin_amdgcn_mfma_f32_16x16x32_bf16((A), (B), (C), 0, 0, 0)

// One LSTM step: read h from hbuf[RB], write h to hbuf[WB]. TLOC = t & 63.
#define STEP(RB, WB, TLOC) do {                                                   \
    bf16x8 ap0 = *(const bf16x8*)&hbuf[RB][0][kg][col >> 1][col & 1][0];          \
    bf16x8 ap1 = *(const bf16x8*)&hbuf[RB][1][kg][col >> 1][col & 1][0];          \
    bf16x8 fa  = *(const bf16x8*)&fcfrag[TLOC][col >> 1][0];                      \
    if (col & 1) fa = zero8;              /* odd A-rows (h_lo rows) get no gx */  \
    f32x4 acc[4];                                                                 \
    _Pragma("unroll")                                                             \
    for (int n = 0; n < 4; ++n) {                                                 \
        f32x4 a = MFMA16(fa,  whx[n],      biasq[n]);  /* gx+bias, even rows */   \
        a       = MFMA16(ap0, whh_h[n][0], a);                                    \
        a       = MFMA16(ap1, whh_h[n][1], a);                                    \
        a       = MFMA16(ap0, whh_l[n][0], a);                                    \
        a       = MFMA16(ap1, whh_l[n][1], a);                                    \
        acc[n] = a;                                                               \
    }                                                                             \
    _Pragma("unroll")                                                             \
    for (int j = 0; j < 2; ++j) {                                                 \
        /* preact row (2kg+j) = hi-row + lo-row = adjacent regs, lane-local */    \
        float Ai = clamp30(acc[0][2 * j] + acc[0][2 * j + 1]);                    \
        float Ff = clamp30(acc[1][2 * j] + acc[1][2 * j + 1]);                    \
        float Gg = clamp30(acc[2][2 * j] + acc[2][2 * j + 1]);                    \
        float Oo = clamp30(acc[3][2 * j] + acc[3][2 * j + 1]);                    \
        float ea = EXP2F(-Ai), ef = EXP2F(-Ff), eg = EXP2F(Gg), eo = EXP2F(-Oo);  \
        float tf  = 1.0f + ef;                                                    \
        float tag = (1.0f + ea) * (1.0f + eg);                                    \
        float Nn  = fmaf(cst[j], tag, (eg - 1.0f) * tf);                          \
        float cn  = Nn * RCPF(tag * tf);                                          \
        cst[j] = cn;                                                              \
        float ec  = EXP2F(clamp30(TWO_LOG2E * cn));                               \
        float hvv = (ec - 1.0f) * RCPF((1.0f + eo) * (ec + 1.0f));                \
        hlast[j] = hvv;                                                           \
        __bf16 hh = (__bf16)hvv; __bf16 hl = (__bf16)(hvv - (float)hh);           \
        hbuf[WB][uks][ukg][2 * kg + j][0][up] = hh;                               \
        hbuf[WB][uks][ukg][2 * kg + j][1][up] = hl;                               \
    }                                                                             \
    __syncthreads();                                                              \
} while (0)

__global__ __launch_bounds__(256, 2)
void lstm_fused(const float* __restrict__ x,
                const float* __restrict__ W1, const float* __restrict__ b1,
                const float* __restrict__ W_ih, const float* __restrict__ W_hh,
                const float* __restrict__ b_ih, const float* __restrict__ b_hh,
                const float* __restrict__ W2, const float* __restrict__ b2,
                float* __restrict__ out)
{
    // fc1 A-fragments: [t][row 0..7][ f_hi(4) | f_lo(4) ]   (8 KB)
    __shared__ __bf16 fcfrag[CHUNK][TB][8];
    // h ping-pong, interleaved hi/lo A-rows, k-grouped:
    // [buf][ks][kg][r 0..7][plane hi/lo][j]   (4 KB)
    __shared__ __bf16 hbuf[2][2][4][8][2][8];
    // final h for output projection: [unit][row]   (2 KB)
    __shared__ float hfin[64][TB];

    const int tid  = threadIdx.x;
    const int lane = tid & 63;
    const int wv   = tid >> 6;     // wave 0..3
    const int col  = lane & 15;    // A-row index / D-col
    const int kg   = lane >> 4;    // k-group 0..3
    const int b0   = blockIdx.x * TB;

    bf16x8 zero8;
    #pragma unroll
    for (int j = 0; j < 8; ++j) zero8[j] = (__bf16)0.0f;

    // ---- weights (LOG2E-pre-scaled), resident in VGPRs ----
    // wave wv owns N-tiles {wv, wv+4, wv+8, wv+12}: gate n rows 64n + u
    bf16x8 whh_h[4][2], whh_l[4][2];  // W_hh hi/lo per gate/kstep
    bf16x8 whx[4];                    // gx B-frag: kg0=[Whi|Whi], kg1=[Wlo|Wlo], else 0
    f32x4  biasq[4];                  // bias on EVEN regs only (even D rows)

    #pragma unroll
    for (int n = 0; n < 4; ++n) {
        const int g = 16 * (wv + 4 * n) + col;          // n: 0=i,1=f,2=g,3=o
        const float sc = (n == 2) ? TWO_LOG2E : LOG2E;
        #pragma unroll
        for (int ks = 0; ks < 2; ++ks) {
            const float* wp = &W_hh[g * 64 + ks * 32 + kg * 8];
            #pragma unroll
            for (int j = 0; j < 8; ++j) {
                float wf  = sc * wp[j];
                __bf16 hi = (__bf16)wf;
                whh_h[n][ks][j] = hi;
                whh_l[n][ks][j] = (__bf16)(wf - (float)hi);
            }
        }
        whx[n] = zero8;
        if (kg < 2) {
            #pragma unroll
            for (int j = 0; j < 4; ++j) {
                float wf  = sc * W_ih[g * 4 + j];
                __bf16 hi = (__bf16)wf;
                __bf16 v  = (kg == 0) ? hi : (__bf16)(wf - (float)hi);
                whx[n][j] = v; whx[n][j + 4] = v;
            }
        }
        const float bs = sc * (b_ih[g] + b_hh[g]);
        biasq[n][0] = bs; biasq[n][1] = 0.0f;     // odd D rows: no bias
        biasq[n][2] = bs; biasq[n][3] = 0.0f;
    }

    // zero hbuf (4 KB = 256 f32x4): h0 = 0, both buffers
    {
        f32x4 zv = {0.f, 0.f, 0.f, 0.f};
        ((f32x4*)&hbuf[0][0][0][0][0][0])[tid] = zv;
    }

    float w1r[4], b1r[4];
    #pragma unroll
    for (int j = 0; j < 4; ++j) { w1r[j] = W1[j]; b1r[j] = b1[j]; }

    f32x2 cst = {0.f, 0.f};       // c for rows {2kg, 2kg+1}, unit u
    float hlast[2];

    const int u   = 16 * wv + col;    // this lane's h-unit
    const int uks = u >> 5, ukg = (u >> 3) & 3, up = u & 7;

    for (int t = 0; t < S_LEN; t += 2) {
        if ((t & (CHUNK - 1)) == 0) {
            __syncthreads();   // prior chunk's fcfrag reads done (covers init at t=0)
            const int rr = tid & 7;
            const int tq = tid >> 3;         // 0..31, 2 steps each
            f32x2 xv = *(const f32x2*)&x[(b0 + rr) * S_LEN + t + tq * 2];
            #pragma unroll
            for (int tl = 0; tl < 2; ++tl) {
                bf16x8 v;
                #pragma unroll
                for (int j = 0; j < 4; ++j) {
                    float fc  = fast_tanh(xv[tl] * w1r[j] + b1r[j]);
                    __bf16 hi = (__bf16)fc;
                    v[j]     = hi;
                    v[j + 4] = (__bf16)(fc - (float)hi);
                }
                *(bf16x8*)&fcfrag[tq * 2 + tl][rr][0] = v;
            }
            __syncthreads();
        }
        STEP(0, 1, (t & (CHUNK - 1)));
        STEP(1, 0, ((t + 1) & (CHUNK - 1)));
    }

    // epilogue: out[b] = h_last . W2 + b2
    hfin[u][2 * kg + 0] = hlast[0];
    hfin[u][2 * kg + 1] = hlast[1];
    __syncthreads();
    if (tid < TB) {
        float s = b2[0];
        #pragma unroll
        for (int uu = 0; uu < 64; ++uu) s += hfin[uu][tid] * W2[uu];
        out[b0 + tid] = s;
    }
}

extern "C" void kernel_launch(void* const* d_in, const int* in_sizes, int n_in,
                              void* d_out, int out_size, void* d_ws, size_t ws_size,
                              hipStream_t stream) {
    (void)in_sizes; (void)n_in; (void)d_ws; (void)ws_size; (void)out_size;
    const float* x    = (const float*)d_in[0];
    const float* W1   = (const float*)d_in[1];
    const float* b1   = (const float*)d_in[2];
    const float* W_ih = (const float*)d_in[3];
    const float* W_hh = (const float*)d_in[4];
    const float* b_ih = (const float*)d_in[5];
    const float* b_hh = (const float*)d_in[6];
    const float* W2   = (const float*)d_in[7];
    const float* b2   = (const float*)d_in[8];
    float* out = (float*)d_out;
    lstm_fused<<<4096 / TB, 256, 0, stream>>>(x, W1, b1, W_ih, W_hh, b_ih, b_hh, W2, b2, out);
}